// Round 3
// baseline (924.249 us; speedup 1.0000x reference)
//
#include <hip/hip_runtime.h>
#include <cmath>

#define KW    11
#define PADW  5
#define BX    64
#define BY    16
#define TR    (BY + 2*PADW)   // 26 h-blur rows per tile
#define HST   68              // padded LDS row stride (floats)
#define IMG   512
#define NPIX  25165824.0      // 32*3*512*512

struct GaussW { float g[6]; };   // symmetric 11-tap, g[k]=g[10-k]

// Horizontal pass: one task per thread (TR*8 = 208 tasks), each task produces
// 8 h-blurred outputs for the 5 quantities {x1, x2, x1^2, x2^2, x1*x2}.
// CHK=false is the interior fast path (no per-lane bounds checks).
template<bool CHK>
__device__ __forceinline__ void hpass(const float* __restrict__ base1,
                                      const float* __restrict__ base2,
                                      int x0, int y0, const GaussW& gw,
                                      float (&hb)[5][TR][HST], int tid) {
  if (tid < TR * 8) {
    const int r = tid >> 3;
    const int g = tid & 7;
    const int gy = y0 - PADW + r;
    const int xb = x0 + 8 * g - 8;        // 24-float raw window start

    float a[24], b[24];
    if (CHK) {
      const bool rowok = ((unsigned)gy < (unsigned)IMG);
      #pragma unroll
      for (int i = 0; i < 6; i++) {
        const int cb = xb + 4 * i;
        if (rowok && ((unsigned)cb < (unsigned)IMG)) {
          const float4 v1 = *(const float4*)(base1 + (size_t)gy * IMG + cb);
          const float4 v2 = *(const float4*)(base2 + (size_t)gy * IMG + cb);
          a[4*i+0] = fmaf(v1.x, 0.5f, 0.5f);  b[4*i+0] = fmaf(v2.x, 0.5f, 0.5f);
          a[4*i+1] = fmaf(v1.y, 0.5f, 0.5f);  b[4*i+1] = fmaf(v2.y, 0.5f, 0.5f);
          a[4*i+2] = fmaf(v1.z, 0.5f, 0.5f);  b[4*i+2] = fmaf(v2.z, 0.5f, 0.5f);
          a[4*i+3] = fmaf(v1.w, 0.5f, 0.5f);  b[4*i+3] = fmaf(v2.w, 0.5f, 0.5f);
        } else {
          a[4*i+0] = 0.f; a[4*i+1] = 0.f; a[4*i+2] = 0.f; a[4*i+3] = 0.f;
          b[4*i+0] = 0.f; b[4*i+1] = 0.f; b[4*i+2] = 0.f; b[4*i+3] = 0.f;
        }
      }
    } else {
      const float* p1 = base1 + (size_t)gy * IMG + xb;
      const float* p2 = base2 + (size_t)gy * IMG + xb;
      #pragma unroll
      for (int i = 0; i < 6; i++) {
        const float4 v1 = *(const float4*)(p1 + 4 * i);
        const float4 v2 = *(const float4*)(p2 + 4 * i);
        a[4*i+0] = fmaf(v1.x, 0.5f, 0.5f);  b[4*i+0] = fmaf(v2.x, 0.5f, 0.5f);
        a[4*i+1] = fmaf(v1.y, 0.5f, 0.5f);  b[4*i+1] = fmaf(v2.y, 0.5f, 0.5f);
        a[4*i+2] = fmaf(v1.z, 0.5f, 0.5f);  b[4*i+2] = fmaf(v2.z, 0.5f, 0.5f);
        a[4*i+3] = fmaf(v1.w, 0.5f, 0.5f);  b[4*i+3] = fmaf(v2.w, 0.5f, 0.5f);
      }
    }

    // products once per raw point
    float p11[18], p22[18], p12[18];
    #pragma unroll
    for (int i = 0; i < 18; i++) {
      const float u = a[i + 3], v = b[i + 3];
      p11[i] = u * u; p22[i] = v * v; p12[i] = u * v;
    }

    float c0[8], c1[8], c2[8], c3[8], c4[8];
    #pragma unroll
    for (int j = 0; j < 8; j++) { c0[j]=0.f; c1[j]=0.f; c2[j]=0.f; c3[j]=0.f; c4[j]=0.f; }
    #pragma unroll
    for (int k = 0; k < KW; k++) {
      const float gk = gw.g[(k < 6) ? k : 10 - k];
      #pragma unroll
      for (int j = 0; j < 8; j++) {
        c0[j] = fmaf(gk, a[j + 3 + k], c0[j]);
        c1[j] = fmaf(gk, b[j + 3 + k], c1[j]);
        c2[j] = fmaf(gk, p11[j + k], c2[j]);
        c3[j] = fmaf(gk, p22[j + k], c3[j]);
        c4[j] = fmaf(gk, p12[j + k], c4[j]);
      }
    }

    const int col = 8 * g;
    *(float4*)&hb[0][r][col]     = make_float4(c0[0], c0[1], c0[2], c0[3]);
    *(float4*)&hb[0][r][col + 4] = make_float4(c0[4], c0[5], c0[6], c0[7]);
    *(float4*)&hb[1][r][col]     = make_float4(c1[0], c1[1], c1[2], c1[3]);
    *(float4*)&hb[1][r][col + 4] = make_float4(c1[4], c1[5], c1[6], c1[7]);
    *(float4*)&hb[2][r][col]     = make_float4(c2[0], c2[1], c2[2], c2[3]);
    *(float4*)&hb[2][r][col + 4] = make_float4(c2[4], c2[5], c2[6], c2[7]);
    *(float4*)&hb[3][r][col]     = make_float4(c3[0], c3[1], c3[2], c3[3]);
    *(float4*)&hb[3][r][col + 4] = make_float4(c3[4], c3[5], c3[6], c3[7]);
    *(float4*)&hb[4][r][col]     = make_float4(c4[0], c4[1], c4[2], c4[3]);
    *(float4*)&hb[4][r][col + 4] = make_float4(c4[4], c4[5], c4[6], c4[7]);
  }
}

__global__ __launch_bounds__(256, 4)
void ssim_main(const float* __restrict__ img1, const float* __restrict__ img2,
               double* __restrict__ acc, GaussW gw) {
  __shared__ float hb[5][TR][HST];   // 35.4 KB -> 4 blocks/CU
  __shared__ float red[4];

  const int tid = threadIdx.x;
  const int tx = blockIdx.x & 7;
  const int ty = blockIdx.x >> 3;
  const int x0 = tx * BX;
  const int y0 = ty * BY;
  const size_t plane = (size_t)blockIdx.y * (IMG * IMG);
  const float* base1 = img1 + plane;
  const float* base2 = img2 + plane;

  // ---------------- horizontal pass ----------------
  // interior blocks (70%): no bounds checks needed anywhere in the window
  if (tx >= 1 && tx <= 6 && ty >= 1 && ty <= 30) {
    hpass<false>(base1, base2, x0, y0, gw, hb, tid);
  } else {
    hpass<true>(base1, base2, x0, y0, gw, hb, tid);
  }

  __syncthreads();

  // ---------------- vertical pass ----------------
  // wave w handles output rows [4w, 4w+4), lane c = column; rolling 11-row
  // register window => 5 LDS reads per new row.
  const int w = tid >> 6;
  const int c = tid & 63;
  const int ys = 4 * w;

  const float C1 = (float)(0.01 * 0.01);
  const float C2 = (float)(0.03 * 0.03);

  float win[5][11];
  #pragma unroll
  for (int t = 0; t < 10; t++) {
    #pragma unroll
    for (int q = 0; q < 5; q++) win[q][t] = hb[q][ys + t][c];
  }

  float accs = 0.f;
  #pragma unroll
  for (int i = 0; i < 4; i++) {
    #pragma unroll
    for (int q = 0; q < 5; q++) win[q][(10 + i) % 11] = hb[q][ys + 10 + i][c];

    float vb[5];
    #pragma unroll
    for (int q = 0; q < 5; q++) {
      float s = 0.f;
      #pragma unroll
      for (int k = 0; k < KW; k++) {
        const float gk = gw.g[(k < 6) ? k : 10 - k];
        s = fmaf(gk, win[q][(i + k) % 11], s);
      }
      vb[q] = s;
    }

    const float mu1 = vb[0], mu2 = vb[1];
    const float m11 = mu1 * mu1, m22 = mu2 * mu2, m12 = mu1 * mu2;
    const float s11 = vb[2] - m11;
    const float s22 = vb[3] - m22;
    const float s12 = vb[4] - m12;
    const float num = fmaf(2.f, m12, C1) * fmaf(2.f, s12, C2);
    const float den = (m11 + m22 + C1) * (s11 + s22 + C2);
    accs += num / den;
  }

  // ---------------- reduction ----------------
  float s = accs;
  #pragma unroll
  for (int m = 32; m >= 1; m >>= 1) s += __shfl_xor(s, m, 64);
  if (c == 0) red[w] = s;
  __syncthreads();
  if (tid == 0) {
    const double bs = (double)red[0] + (double)red[1] + (double)red[2] + (double)red[3];
    atomicAdd(acc, bs);
  }
}

__global__ void ssim_fin(const double* __restrict__ acc, float* __restrict__ out) {
  out[0] = 1.0f - (float)(acc[0] * (1.0 / NPIX));
}

extern "C" void kernel_launch(void* const* d_in, const int* in_sizes, int n_in,
                              void* d_out, int out_size, void* d_ws, size_t ws_size,
                              hipStream_t stream) {
  const float* img1 = (const float*)d_in[0];
  const float* img2 = (const float*)d_in[1];
  float* out = (float*)d_out;
  double* acc = (double*)d_ws;

  // ws is poisoned 0xAA before every timed launch — zero the accumulator.
  hipMemsetAsync(acc, 0, sizeof(double), stream);

  GaussW gw;
  {
    double e[11], s = 0.0;
    for (int i = 0; i < 11; i++) {
      const double x = (double)(i - 5);
      e[i] = exp(-(x * x) / (2.0 * 1.5 * 1.5));
      s += e[i];
    }
    for (int i = 0; i < 6; i++) gw.g[i] = (float)(e[i] / s);
  }

  dim3 grid(256, 96);   // 8x32 tiles per plane, 96 planes
  ssim_main<<<grid, 256, 0, stream>>>(img1, img2, acc, gw);
  ssim_fin<<<1, 1, 0, stream>>>(acc, out);
}

// Round 4
// 471.547 us; speedup vs baseline: 1.9600x; 1.9600x over previous
//
#include <hip/hip_runtime.h>
#include <cmath>

#define KW    11
#define PADW  5
#define BX    64
#define BY    16
#define TR    (BY + 2*PADW)   // 26 h-blur rows per tile
#define HST   68              // padded LDS row stride (floats)
#define IMG   512
#define NPIX  25165824.0      // 32*3*512*512

struct GaussW { float g[6]; };   // symmetric 11-tap, g[k]=g[10-k]

// Horizontal pass: one task per thread (TR*8 = 208 tasks), each task produces
// 8 h-blurred outputs for the 5 quantities {x1, x2, x1^2, x2^2, x1*x2}.
// CHK=false is the interior fast path (no per-lane bounds checks).
template<bool CHK>
__device__ __forceinline__ void hpass(const float* __restrict__ base1,
                                      const float* __restrict__ base2,
                                      int x0, int y0, const GaussW& gw,
                                      float (&hb)[5][TR][HST], int tid) {
  if (tid < TR * 8) {
    const int r = tid >> 3;
    const int g = tid & 7;
    const int gy = y0 - PADW + r;
    const int xb = x0 + 8 * g - 8;        // 24-float raw window start

    float a[24], b[24];
    if (CHK) {
      const bool rowok = ((unsigned)gy < (unsigned)IMG);
      #pragma unroll
      for (int i = 0; i < 6; i++) {
        const int cb = xb + 4 * i;
        if (rowok && ((unsigned)cb < (unsigned)IMG)) {
          const float4 v1 = *(const float4*)(base1 + (size_t)gy * IMG + cb);
          const float4 v2 = *(const float4*)(base2 + (size_t)gy * IMG + cb);
          a[4*i+0] = fmaf(v1.x, 0.5f, 0.5f);  b[4*i+0] = fmaf(v2.x, 0.5f, 0.5f);
          a[4*i+1] = fmaf(v1.y, 0.5f, 0.5f);  b[4*i+1] = fmaf(v2.y, 0.5f, 0.5f);
          a[4*i+2] = fmaf(v1.z, 0.5f, 0.5f);  b[4*i+2] = fmaf(v2.z, 0.5f, 0.5f);
          a[4*i+3] = fmaf(v1.w, 0.5f, 0.5f);  b[4*i+3] = fmaf(v2.w, 0.5f, 0.5f);
        } else {
          a[4*i+0] = 0.f; a[4*i+1] = 0.f; a[4*i+2] = 0.f; a[4*i+3] = 0.f;
          b[4*i+0] = 0.f; b[4*i+1] = 0.f; b[4*i+2] = 0.f; b[4*i+3] = 0.f;
        }
      }
    } else {
      const float* p1 = base1 + (size_t)gy * IMG + xb;
      const float* p2 = base2 + (size_t)gy * IMG + xb;
      #pragma unroll
      for (int i = 0; i < 6; i++) {
        const float4 v1 = *(const float4*)(p1 + 4 * i);
        const float4 v2 = *(const float4*)(p2 + 4 * i);
        a[4*i+0] = fmaf(v1.x, 0.5f, 0.5f);  b[4*i+0] = fmaf(v2.x, 0.5f, 0.5f);
        a[4*i+1] = fmaf(v1.y, 0.5f, 0.5f);  b[4*i+1] = fmaf(v2.y, 0.5f, 0.5f);
        a[4*i+2] = fmaf(v1.z, 0.5f, 0.5f);  b[4*i+2] = fmaf(v2.z, 0.5f, 0.5f);
        a[4*i+3] = fmaf(v1.w, 0.5f, 0.5f);  b[4*i+3] = fmaf(v2.w, 0.5f, 0.5f);
      }
    }

    // products once per raw point
    float p11[18], p22[18], p12[18];
    #pragma unroll
    for (int i = 0; i < 18; i++) {
      const float u = a[i + 3], v = b[i + 3];
      p11[i] = u * u; p22[i] = v * v; p12[i] = u * v;
    }

    float c0[8], c1[8], c2[8], c3[8], c4[8];
    #pragma unroll
    for (int j = 0; j < 8; j++) { c0[j]=0.f; c1[j]=0.f; c2[j]=0.f; c3[j]=0.f; c4[j]=0.f; }
    #pragma unroll
    for (int k = 0; k < KW; k++) {
      const float gk = gw.g[(k < 6) ? k : 10 - k];
      #pragma unroll
      for (int j = 0; j < 8; j++) {
        c0[j] = fmaf(gk, a[j + 3 + k], c0[j]);
        c1[j] = fmaf(gk, b[j + 3 + k], c1[j]);
        c2[j] = fmaf(gk, p11[j + k], c2[j]);
        c3[j] = fmaf(gk, p22[j + k], c3[j]);
        c4[j] = fmaf(gk, p12[j + k], c4[j]);
      }
    }

    const int col = 8 * g;
    *(float4*)&hb[0][r][col]     = make_float4(c0[0], c0[1], c0[2], c0[3]);
    *(float4*)&hb[0][r][col + 4] = make_float4(c0[4], c0[5], c0[6], c0[7]);
    *(float4*)&hb[1][r][col]     = make_float4(c1[0], c1[1], c1[2], c1[3]);
    *(float4*)&hb[1][r][col + 4] = make_float4(c1[4], c1[5], c1[6], c1[7]);
    *(float4*)&hb[2][r][col]     = make_float4(c2[0], c2[1], c2[2], c2[3]);
    *(float4*)&hb[2][r][col + 4] = make_float4(c2[4], c2[5], c2[6], c2[7]);
    *(float4*)&hb[3][r][col]     = make_float4(c3[0], c3[1], c3[2], c3[3]);
    *(float4*)&hb[3][r][col + 4] = make_float4(c3[4], c3[5], c3[6], c3[7]);
    *(float4*)&hb[4][r][col]     = make_float4(c4[0], c4[1], c4[2], c4[3]);
    *(float4*)&hb[4][r][col + 4] = make_float4(c4[4], c4[5], c4[6], c4[7]);
  }
}

// NOTE: min-waves/EU kept at 2 (VGPR cap 256). Forcing 4 here drove the
// allocator to 64 VGPRs -> 2 GB of scratch spill traffic (R3: 808 us).
// At the natural ~88 VGPRs the HW already fits 4 waves/SIMD; occupancy is
// LDS-limited (35.8 KB -> 4 blocks/CU), which is what we want.
__global__ __launch_bounds__(256, 2)
void ssim_main(const float* __restrict__ img1, const float* __restrict__ img2,
               double* __restrict__ acc, GaussW gw) {
  __shared__ float hb[5][TR][HST];   // 35.4 KB -> 4 blocks/CU
  __shared__ float red[4];

  const int tid = threadIdx.x;
  const int tx = blockIdx.x & 7;
  const int ty = blockIdx.x >> 3;
  const int x0 = tx * BX;
  const int y0 = ty * BY;
  const size_t plane = (size_t)blockIdx.y * (IMG * IMG);
  const float* base1 = img1 + plane;
  const float* base2 = img2 + plane;

  // ---------------- horizontal pass ----------------
  // interior blocks (70%): no bounds checks needed anywhere in the window
  if (tx >= 1 && tx <= 6 && ty >= 1 && ty <= 30) {
    hpass<false>(base1, base2, x0, y0, gw, hb, tid);
  } else {
    hpass<true>(base1, base2, x0, y0, gw, hb, tid);
  }

  __syncthreads();

  // ---------------- vertical pass ----------------
  // wave w handles output rows [4w, 4w+4), lane c = column; rolling 11-row
  // register window => 5 LDS reads per new row.
  const int w = tid >> 6;
  const int c = tid & 63;
  const int ys = 4 * w;

  const float C1 = (float)(0.01 * 0.01);
  const float C2 = (float)(0.03 * 0.03);

  float win[5][11];
  #pragma unroll
  for (int t = 0; t < 10; t++) {
    #pragma unroll
    for (int q = 0; q < 5; q++) win[q][t] = hb[q][ys + t][c];
  }

  float accs = 0.f;
  #pragma unroll
  for (int i = 0; i < 4; i++) {
    #pragma unroll
    for (int q = 0; q < 5; q++) win[q][(10 + i) % 11] = hb[q][ys + 10 + i][c];

    float vb[5];
    #pragma unroll
    for (int q = 0; q < 5; q++) {
      float s = 0.f;
      #pragma unroll
      for (int k = 0; k < KW; k++) {
        const float gk = gw.g[(k < 6) ? k : 10 - k];
        s = fmaf(gk, win[q][(i + k) % 11], s);
      }
      vb[q] = s;
    }

    const float mu1 = vb[0], mu2 = vb[1];
    const float m11 = mu1 * mu1, m22 = mu2 * mu2, m12 = mu1 * mu2;
    const float s11 = vb[2] - m11;
    const float s22 = vb[3] - m22;
    const float s12 = vb[4] - m12;
    const float num = fmaf(2.f, m12, C1) * fmaf(2.f, s12, C2);
    const float den = (m11 + m22 + C1) * (s11 + s22 + C2);
    accs += num / den;
  }

  // ---------------- reduction ----------------
  float s = accs;
  #pragma unroll
  for (int m = 32; m >= 1; m >>= 1) s += __shfl_xor(s, m, 64);
  if (c == 0) red[w] = s;
  __syncthreads();
  if (tid == 0) {
    const double bs = (double)red[0] + (double)red[1] + (double)red[2] + (double)red[3];
    atomicAdd(acc, bs);
  }
}

__global__ void ssim_fin(const double* __restrict__ acc, float* __restrict__ out) {
  out[0] = 1.0f - (float)(acc[0] * (1.0 / NPIX));
}

extern "C" void kernel_launch(void* const* d_in, const int* in_sizes, int n_in,
                              void* d_out, int out_size, void* d_ws, size_t ws_size,
                              hipStream_t stream) {
  const float* img1 = (const float*)d_in[0];
  const float* img2 = (const float*)d_in[1];
  float* out = (float*)d_out;
  double* acc = (double*)d_ws;

  // ws is poisoned 0xAA before every timed launch — zero the accumulator.
  hipMemsetAsync(acc, 0, sizeof(double), stream);

  GaussW gw;
  {
    double e[11], s = 0.0;
    for (int i = 0; i < 11; i++) {
      const double x = (double)(i - 5);
      e[i] = exp(-(x * x) / (2.0 * 1.5 * 1.5));
      s += e[i];
    }
    for (int i = 0; i < 6; i++) gw.g[i] = (float)(e[i] / s);
  }

  dim3 grid(256, 96);   // 8x32 tiles per plane, 96 planes
  ssim_main<<<grid, 256, 0, stream>>>(img1, img2, acc, gw);
  ssim_fin<<<1, 1, 0, stream>>>(acc, out);
}

// Round 5
// 317.287 us; speedup vs baseline: 2.9130x; 1.4862x over previous
//
#include <hip/hip_runtime.h>
#include <cmath>

#define KW    11
#define PADW  5
#define BX    64
#define BY    32
#define TR    (BY + 2*PADW)   // 42 h-blur rows per tile
#define HST   72              // ushort stride per row = 144 B (16B-aligned)
#define IMG   512
#define NPIX  25165824.0      // 32*3*512*512

struct GaussW { float g[6]; };   // symmetric 11-tap, g[k]=g[10-k]

// round-half-up f32 -> bf16, packed pair into one u32
__device__ __forceinline__ unsigned pack_bf16(float x0, float x1) {
  const unsigned u0 = __float_as_uint(x0);
  const unsigned u1 = __float_as_uint(x1);
  return ((u0 + 0x8000u) >> 16) | ((u1 + 0x8000u) & 0xFFFF0000u);
}

__device__ __forceinline__ float bf2f(unsigned short h) {
  return __uint_as_float(((unsigned)h) << 16);
}

// Horizontal pass: tasks t in [0, TR*8): row r = t>>3, col-group g = t&7.
// Each task produces 8 h-blurred bf16 outputs for the 5 quantities
// {x1, x2, x1^2, x2^2, x1*x2}. CHK=false: interior fast path.
template<bool CHK>
__device__ __forceinline__ void hpass(const float* __restrict__ base1,
                                      const float* __restrict__ base2,
                                      int x0, int y0, const GaussW& gw,
                                      unsigned short (&hb)[5][TR][HST], int tid) {
  for (int t = tid; t < TR * 8; t += 256) {
    const int r = t >> 3;
    const int g = t & 7;
    const int gy = y0 - PADW + r;
    const int xb = x0 + 8 * g - 8;        // 24-float raw window start

    float a[24], b[24];
    if (CHK) {
      const bool rowok = ((unsigned)gy < (unsigned)IMG);
      #pragma unroll
      for (int i = 0; i < 6; i++) {
        const int cb = xb + 4 * i;
        if (rowok && ((unsigned)cb < (unsigned)IMG)) {
          const float4 v1 = *(const float4*)(base1 + (size_t)gy * IMG + cb);
          const float4 v2 = *(const float4*)(base2 + (size_t)gy * IMG + cb);
          a[4*i+0] = fmaf(v1.x, 0.5f, 0.5f);  b[4*i+0] = fmaf(v2.x, 0.5f, 0.5f);
          a[4*i+1] = fmaf(v1.y, 0.5f, 0.5f);  b[4*i+1] = fmaf(v2.y, 0.5f, 0.5f);
          a[4*i+2] = fmaf(v1.z, 0.5f, 0.5f);  b[4*i+2] = fmaf(v2.z, 0.5f, 0.5f);
          a[4*i+3] = fmaf(v1.w, 0.5f, 0.5f);  b[4*i+3] = fmaf(v2.w, 0.5f, 0.5f);
        } else {
          a[4*i+0] = 0.f; a[4*i+1] = 0.f; a[4*i+2] = 0.f; a[4*i+3] = 0.f;
          b[4*i+0] = 0.f; b[4*i+1] = 0.f; b[4*i+2] = 0.f; b[4*i+3] = 0.f;
        }
      }
    } else {
      const float* p1 = base1 + (size_t)gy * IMG + xb;
      const float* p2 = base2 + (size_t)gy * IMG + xb;
      #pragma unroll
      for (int i = 0; i < 6; i++) {
        const float4 v1 = *(const float4*)(p1 + 4 * i);
        const float4 v2 = *(const float4*)(p2 + 4 * i);
        a[4*i+0] = fmaf(v1.x, 0.5f, 0.5f);  b[4*i+0] = fmaf(v2.x, 0.5f, 0.5f);
        a[4*i+1] = fmaf(v1.y, 0.5f, 0.5f);  b[4*i+1] = fmaf(v2.y, 0.5f, 0.5f);
        a[4*i+2] = fmaf(v1.z, 0.5f, 0.5f);  b[4*i+2] = fmaf(v2.z, 0.5f, 0.5f);
        a[4*i+3] = fmaf(v1.w, 0.5f, 0.5f);  b[4*i+3] = fmaf(v2.w, 0.5f, 0.5f);
      }
    }

    // products once per raw point
    float p11[18], p22[18], p12[18];
    #pragma unroll
    for (int i = 0; i < 18; i++) {
      const float u = a[i + 3], v = b[i + 3];
      p11[i] = u * u; p22[i] = v * v; p12[i] = u * v;
    }

    float c0[8], c1[8], c2[8], c3[8], c4[8];
    #pragma unroll
    for (int j = 0; j < 8; j++) { c0[j]=0.f; c1[j]=0.f; c2[j]=0.f; c3[j]=0.f; c4[j]=0.f; }
    #pragma unroll
    for (int k = 0; k < KW; k++) {
      const float gk = gw.g[(k < 6) ? k : 10 - k];
      #pragma unroll
      for (int j = 0; j < 8; j++) {
        c0[j] = fmaf(gk, a[j + 3 + k], c0[j]);
        c1[j] = fmaf(gk, b[j + 3 + k], c1[j]);
        c2[j] = fmaf(gk, p11[j + k], c2[j]);
        c3[j] = fmaf(gk, p22[j + k], c3[j]);
        c4[j] = fmaf(gk, p12[j + k], c4[j]);
      }
    }

    const int col = 8 * g;
    *(uint4*)&hb[0][r][col] = make_uint4(pack_bf16(c0[0],c0[1]), pack_bf16(c0[2],c0[3]),
                                         pack_bf16(c0[4],c0[5]), pack_bf16(c0[6],c0[7]));
    *(uint4*)&hb[1][r][col] = make_uint4(pack_bf16(c1[0],c1[1]), pack_bf16(c1[2],c1[3]),
                                         pack_bf16(c1[4],c1[5]), pack_bf16(c1[6],c1[7]));
    *(uint4*)&hb[2][r][col] = make_uint4(pack_bf16(c2[0],c2[1]), pack_bf16(c2[2],c2[3]),
                                         pack_bf16(c2[4],c2[5]), pack_bf16(c2[6],c2[7]));
    *(uint4*)&hb[3][r][col] = make_uint4(pack_bf16(c3[0],c3[1]), pack_bf16(c3[2],c3[3]),
                                         pack_bf16(c3[4],c3[5]), pack_bf16(c3[6],c3[7]));
    *(uint4*)&hb[4][r][col] = make_uint4(pack_bf16(c4[0],c4[1]), pack_bf16(c4[2],c4[3]),
                                         pack_bf16(c4[4],c4[5]), pack_bf16(c4[6],c4[7]));
  }
}

// NOTE: min-waves/EU = 2 (VGPR cap 256). Forcing 4 drove the allocator to
// 64 VGPRs -> 2 GB scratch spill (R3: 808 us). At ~90 VGPRs the HW fits
// 4 waves/SIMD; occupancy is LDS-limited: 30.2 KB -> 4-5 blocks/CU.
__global__ __launch_bounds__(256, 2)
void ssim_main(const float* __restrict__ img1, const float* __restrict__ img2,
               double* __restrict__ acc, GaussW gw) {
  __shared__ unsigned short hb[5][TR][HST];   // bf16: 30.2 KB
  __shared__ float red[4];

  const int tid = threadIdx.x;
  const int tx = blockIdx.x & 7;
  const int ty = blockIdx.x >> 3;
  const int x0 = tx * BX;
  const int y0 = ty * BY;
  const size_t plane = (size_t)blockIdx.y * (IMG * IMG);
  const float* base1 = img1 + plane;
  const float* base2 = img2 + plane;

  // ---------------- horizontal pass ----------------
  if (tx >= 1 && tx <= 6 && ty >= 1 && ty <= 14) {
    hpass<false>(base1, base2, x0, y0, gw, hb, tid);
  } else {
    hpass<true>(base1, base2, x0, y0, gw, hb, tid);
  }

  __syncthreads();

  // ---------------- vertical pass ----------------
  // wave w: output rows [8w, 8w+8), lane c = column; rolling 11-row register
  // window => 5 LDS u16 reads per new row.
  const int w = tid >> 6;
  const int c = tid & 63;
  const int ys = 8 * w;

  const float C1 = (float)(0.01 * 0.01);
  const float C2 = (float)(0.03 * 0.03);

  float win[5][11];
  #pragma unroll
  for (int t = 0; t < 10; t++) {
    #pragma unroll
    for (int q = 0; q < 5; q++) win[q][t] = bf2f(hb[q][ys + t][c]);
  }

  float accs = 0.f;
  #pragma unroll
  for (int i = 0; i < 8; i++) {
    #pragma unroll
    for (int q = 0; q < 5; q++) win[q][(10 + i) % 11] = bf2f(hb[q][ys + 10 + i][c]);

    float vb[5];
    #pragma unroll
    for (int q = 0; q < 5; q++) {
      float s = 0.f;
      #pragma unroll
      for (int k = 0; k < KW; k++) {
        const float gk = gw.g[(k < 6) ? k : 10 - k];
        s = fmaf(gk, win[q][(i + k) % 11], s);
      }
      vb[q] = s;
    }

    const float mu1 = vb[0], mu2 = vb[1];
    const float m11 = mu1 * mu1, m22 = mu2 * mu2, m12 = mu1 * mu2;
    const float s11 = vb[2] - m11;
    const float s22 = vb[3] - m22;
    const float s12 = vb[4] - m12;
    const float num = fmaf(2.f, m12, C1) * fmaf(2.f, s12, C2);
    const float den = (m11 + m22 + C1) * (s11 + s22 + C2);
    accs += num / den;
  }

  // ---------------- reduction ----------------
  float s = accs;
  #pragma unroll
  for (int m = 32; m >= 1; m >>= 1) s += __shfl_xor(s, m, 64);
  if (c == 0) red[w] = s;
  __syncthreads();
  if (tid == 0) {
    const double bs = (double)red[0] + (double)red[1] + (double)red[2] + (double)red[3];
    atomicAdd(acc, bs);
  }
}

__global__ void ssim_fin(const double* __restrict__ acc, float* __restrict__ out) {
  out[0] = 1.0f - (float)(acc[0] * (1.0 / NPIX));
}

extern "C" void kernel_launch(void* const* d_in, const int* in_sizes, int n_in,
                              void* d_out, int out_size, void* d_ws, size_t ws_size,
                              hipStream_t stream) {
  const float* img1 = (const float*)d_in[0];
  const float* img2 = (const float*)d_in[1];
  float* out = (float*)d_out;
  double* acc = (double*)d_ws;

  // ws is poisoned 0xAA before every timed launch — zero the accumulator.
  hipMemsetAsync(acc, 0, sizeof(double), stream);

  GaussW gw;
  {
    double e[11], s = 0.0;
    for (int i = 0; i < 11; i++) {
      const double x = (double)(i - 5);
      e[i] = exp(-(x * x) / (2.0 * 1.5 * 1.5));
      s += e[i];
    }
    for (int i = 0; i < 6; i++) gw.g[i] = (float)(e[i] / s);
  }

  dim3 grid(128, 96);   // 8x16 tiles per plane, 96 planes
  ssim_main<<<grid, 256, 0, stream>>>(img1, img2, acc, gw);
  ssim_fin<<<1, 1, 0, stream>>>(acc, out);
}